// Round 1
// 832.437 us; speedup vs baseline: 1.0428x; 1.0428x over previous
//
#include <hip/hip_runtime.h>
#include <hip/hip_bf16.h>
#include <stdint.h>

// Problem constants (from reference)
#define N_ENT    100000
#define N_REL    250000
#define N_TRIG   50000
#define N_ARGS   250000
#define ENT_DIM  288
#define REL_R    256
#define RTYPE_DIM 32
#define ROLE_DIM 256
#define ARG_DIM  576           // REL_R + RTYPE_DIM + ENT_DIM
#define OUT_DIM  544           // ENT_DIM + ROLE_DIM

// GEMM tiling
#define BM 64                  // args per block
#define BK 32                  // K chunk (one MFMA K-step)
#define NSTEP (ARG_DIM / BK)   // 18
#define LDP 40                 // padded K-stride in LDS (shorts): 80 B rows,
                               // uniform bank spread for b64 writes / b128 reads

typedef __attribute__((ext_vector_type(8))) short bf16x8;   // 8 bf16 (4 VGPRs)
typedef __attribute__((ext_vector_type(4))) short bf16x4;   // 4 bf16 (2 VGPRs)
typedef __attribute__((ext_vector_type(4))) float f32x4;    // MFMA acc

// f32 -> bf16 (round-to-nearest-even), bit-level
__device__ __forceinline__ short f2b(float f) {
    union { float f; uint32_t u; } v; v.f = f;
    uint32_t u = v.u;
    uint32_t r = (u + 0x7fffu + ((u >> 16) & 1u)) >> 16;
    return (short)r;
}

// Kernel 1: out[t, 0:288] = ent[trig_ent[t]];  out[t, 288:544] = 0.
// One wave per trigger, float4 throughout. 4 triggers / 256-thread block.
__global__ void __launch_bounds__(256)
k_init(const float* __restrict__ ent, const int* __restrict__ trig_ent,
       float* __restrict__ out)
{
    const int t    = blockIdx.x * 4 + (threadIdx.x >> 6);
    const int lane = threadIdx.x & 63;
    const int e    = trig_ent[t];
    const float4* src = (const float4*)(ent + (size_t)e * ENT_DIM);  // 72 f4
    float4*       dst = (float4*)(out + (size_t)t * OUT_DIM);        // 136 f4
    const float4 z = {0.f, 0.f, 0.f, 0.f};
    dst[lane] = src[lane];                         // floats 0..255
    if (lane < 8) dst[64 + lane] = src[64 + lane]; // floats 256..287
    dst[72 + lane] = z;                            // floats 288..543
}

// Kernel 2: convert+transpose W_in/W_out f32[576][256] -> Wb bf16[2][256][576]
// (per-column contiguous k, so B fragment reads are contiguous 16B)
__global__ void __launch_bounds__(256)
k_prep(const float* __restrict__ W_in, const float* __restrict__ W_out,
       short* __restrict__ Wb)
{
    const int idx = blockIdx.x * 256 + threadIdx.x;     // 0 .. 2*576*256-1
    const int w   = idx / (ARG_DIM * ROLE_DIM);
    const int rem = idx % (ARG_DIM * ROLE_DIM);
    const int k   = rem / ROLE_DIM;
    const int col = rem % ROLE_DIM;
    const float* src = (w == 0) ? W_in : W_out;
    Wb[((size_t)w * ROLE_DIM + col) * ARG_DIM + k] = f2b(src[k * ROLE_DIM + col]);
}

// Kernel 3: fused gather + bf16 MFMA GEMM + atomic segment-sum.
//
// 512 threads = 8 waves; M-tile = 64 args; wave w owns cols 32w..32w+31
// (acc[4][2], 32 VGPR). K = 576 in 18 steps of 32.
//
// Pipeline (per K-step, ONE raw barrier, lgkmcnt-only drain):
//   convert+ds_write A slice prefetched 3 steps ago -> As[s&1]
//   s_waitcnt lgkmcnt(0); s_barrier        (vmcnt NOT drained: gathers fly on)
//   ds_read A frags; load B frags direct from L2-resident Wb (no B LDS)
//   masked double-MFMA
//   sched_barrier; issue gather for s+3    (after B loads: in-order vmcnt
//                                           never forces a fresh gather)
// Buffer-reuse safety at distance 2 holds with one barrier/step: store(s+2)
// occurs after barrier(s+1), which all waves reach only after compute(s).
__global__ void __launch_bounds__(512, 4)
k_gemm(const float* __restrict__ ent,  const float* __restrict__ rel,
       const float* __restrict__ rtab, const short* __restrict__ Wb,
       const int* __restrict__ rtype_ids, const int* __restrict__ arg_trig,
       const int* __restrict__ arg_rel,   const int* __restrict__ arg_ent,
       const int* __restrict__ arg_is_in, float* __restrict__ out)
{
    __shared__ short As[2][BM][LDP];     // double-buffered A chunk (10 KB)
    __shared__ int s_rel[BM], s_ent[BM], s_rt[BM], s_trig[BM], s_mask[BM];

    const int tid = threadIdx.x;
    const int a0  = blockIdx.x * BM;

    // Per-arg metadata (mask: 1 = W_in, 0 = W_out, -1 = invalid row)
    if (tid < BM) {
        int a     = a0 + tid;
        int valid = (a < N_ARGS);
        int aa    = valid ? a : (N_ARGS - 1);
        int r     = arg_rel[aa];
        s_rel[tid]  = r;
        s_ent[tid]  = arg_ent[aa];
        s_rt[tid]   = rtype_ids[r];
        s_trig[tid] = arg_trig[aa];
        s_mask[tid] = valid ? arg_is_in[aa] : -1;
    }
    __syncthreads();

    const int lane  = tid & 63;
    const int wave  = tid >> 6;          // 0..7
    const int quad  = lane >> 4;
    const int l15   = lane & 15;
    const int nbase = wave * 32;

    // A-staging coords: thread handles row = tid>>3, 4 floats at (tid&7)*4
    const int srow = tid >> 3;           // 0..63
    const int skq  = (tid & 7) * 4;      // 0..28

    // Per-row gather base pointers (srow fixed per thread)
    const float* p_rel = rel  + (size_t)s_rel[srow] * REL_R    + skq;
    const float* p_rt  = rtab + s_rt[srow] * RTYPE_DIM         + skq;
    const float* p_ent = ent  + (size_t)s_ent[srow] * ENT_DIM  + skq;

    // B fragment base: col = nbase + l15 (+n*16), k = s*32 + quad*8
    const short* wbl = Wb + (size_t)(nbase + l15) * ARG_DIM + quad * 8;

    // A-fragment row for m-tile m is m*16 + l15 -> per-lane scalar mask
    int rowmask[4];
#pragma unroll
    for (int m = 0; m < 4; ++m) rowmask[m] = s_mask[m * 16 + l15];

    f32x4 acc[4][2];
#pragma unroll
    for (int m = 0; m < 4; ++m)
#pragma unroll
        for (int n = 0; n < 2; ++n) acc[m][n] = (f32x4){0.f, 0.f, 0.f, 0.f};

    const bf16x8 zf = {0, 0, 0, 0, 0, 0, 0, 0};

    // 3-deep gather prefetch (steps 0..2 are all in the rel region)
    float4 vA = *(const float4*)(p_rel);
    float4 vB = *(const float4*)(p_rel + BK);
    float4 vC = *(const float4*)(p_rel + 2 * BK);

    auto STEP = [&](int s, float4& w) {
        // ---- convert + store the A slice prefetched 3 steps ago ----
        bf16x4 h;
        h[0] = f2b(w.x); h[1] = f2b(w.y); h[2] = f2b(w.z); h[3] = f2b(w.w);
        *(bf16x4*)&As[s & 1][srow][skq] = h;

        // ---- make LDS writes visible; do NOT drain vmcnt ----
        asm volatile("s_waitcnt lgkmcnt(0)" ::: "memory");
        __builtin_amdgcn_s_barrier();
        asm volatile("" ::: "memory");   // block load hoist above the barrier

        // ---- A fragments from LDS ----
        bf16x8 a[4];
#pragma unroll
        for (int m = 0; m < 4; ++m)
            a[m] = *(const bf16x8*)&As[s & 1][m * 16 + l15][quad * 8];

        // ---- B fragments direct from L2-resident Wb ----
        const short* bp = wbl + s * BK;
        const bf16x8 bi0 = *(const bf16x8*)(bp);
        const bf16x8 bi1 = *(const bf16x8*)(bp + 16 * ARG_DIM);
        const bf16x8 bo0 = *(const bf16x8*)(bp + (size_t)ROLE_DIM * ARG_DIM);
        const bf16x8 bo1 = *(const bf16x8*)(bp + (size_t)(ROLE_DIM + 16) * ARG_DIM);

        // ---- masked double-MFMA ----
#pragma unroll
        for (int m = 0; m < 4; ++m) {
            const bf16x8 ain = (rowmask[m] == 1) ? a[m] : zf;
            const bf16x8 aot = (rowmask[m] == 0) ? a[m] : zf;
            acc[m][0] = __builtin_amdgcn_mfma_f32_16x16x32_bf16(ain, bi0, acc[m][0], 0, 0, 0);
            acc[m][0] = __builtin_amdgcn_mfma_f32_16x16x32_bf16(aot, bo0, acc[m][0], 0, 0, 0);
            acc[m][1] = __builtin_amdgcn_mfma_f32_16x16x32_bf16(ain, bi1, acc[m][1], 0, 0, 0);
            acc[m][1] = __builtin_amdgcn_mfma_f32_16x16x32_bf16(aot, bo1, acc[m][1], 0, 0, 0);
        }

        // ---- issue gather for step s+3 (kept after B loads) ----
        __builtin_amdgcn_sched_barrier(0);
        if (s + 3 < NSTEP) {
            const int sn = s + 3;
            const float* src = (sn < 8)  ? (p_rel + sn * BK)
                             : (sn == 8) ? p_rt
                                         : (p_ent + (sn - 9) * BK);
            w = *(const float4*)src;
        }
    };

#pragma unroll
    for (int ss = 0; ss < NSTEP; ss += 3) {
        STEP(ss,     vA);
        STEP(ss + 1, vB);
        STEP(ss + 2, vC);
    }

    // ---- epilogue: atomic segment-sum into out[:, 288:544] ----
    // C/D layout: col = lane&15, row = quad*4 + reg  [m89-verified]
#pragma unroll
    for (int m = 0; m < 4; ++m) {
#pragma unroll
        for (int r4 = 0; r4 < 4; ++r4) {
            const int row = m * 16 + quad * 4 + r4;
            if (s_mask[row] < 0) continue;           // padded row
            float* dst = out + (size_t)s_trig[row] * OUT_DIM + ENT_DIM
                             + nbase + l15;
            atomicAdd(dst,      acc[m][0][r4]);
            atomicAdd(dst + 16, acc[m][1][r4]);
        }
    }
}

extern "C" void kernel_launch(void* const* d_in, const int* in_sizes, int n_in,
                              void* d_out, int out_size, void* d_ws, size_t ws_size,
                              hipStream_t stream)
{
    const float* ent      = (const float*)d_in[0];   // [N_ENT, 288]
    const float* rel      = (const float*)d_in[1];   // [N_REL, 256]
    const float* rtab     = (const float*)d_in[2];   // [201, 32]
    const float* W_in     = (const float*)d_in[3];   // [576, 256]
    const float* W_out    = (const float*)d_in[4];   // [576, 256]
    const int*  rtype_ids = (const int*)d_in[5];
    const int*  trig_ent  = (const int*)d_in[6];
    const int*  arg_trig  = (const int*)d_in[7];
    const int*  arg_rel   = (const int*)d_in[8];
    const int*  arg_ent   = (const int*)d_in[9];
    const int*  arg_is_in = (const int*)d_in[10];

    float* out = (float*)d_out;                      // [N_TRIG, 544] f32
    short* Wb  = (short*)d_ws;                       // [2][256][576] bf16, 576 KB

    hipLaunchKernelGGL(k_init, dim3(N_TRIG / 4), dim3(256), 0, stream,
                       ent, trig_ent, out);
    hipLaunchKernelGGL(k_prep, dim3(2 * ARG_DIM * ROLE_DIM / 256), dim3(256), 0,
                       stream, W_in, W_out, Wb);
    hipLaunchKernelGGL(k_gemm, dim3((N_ARGS + BM - 1) / BM), dim3(512), 0, stream,
                       ent, rel, rtab, Wb,
                       rtype_ids, arg_trig, arg_rel, arg_ent, arg_is_in, out);
}

// Round 2
// 801.480 us; speedup vs baseline: 1.0831x; 1.0386x over previous
//
#include <hip/hip_runtime.h>
#include <hip/hip_bf16.h>
#include <stdint.h>

// Problem constants (from reference)
#define N_ENT    100000
#define N_REL    250000
#define N_TRIG   50000
#define N_ARGS   250000
#define ENT_DIM  288
#define REL_R    256
#define RTYPE_DIM 32
#define ROLE_DIM 256
#define ARG_DIM  576           // REL_R + RTYPE_DIM + ENT_DIM
#define OUT_DIM  544           // ENT_DIM + ROLE_DIM

// GEMM tiling
#define BM 64                  // args per block
#define BK 32                  // K chunk (one MFMA K-step)
#define NSTEP (ARG_DIM / BK)   // 18
#define LDP 40                 // padded K-stride in LDS (shorts)
#define CSP 258                // Cs padded row stride (floats): 8q+l15 banks -> <=2-way

typedef __attribute__((ext_vector_type(8))) short bf16x8;   // 8 bf16 (4 VGPRs)
typedef __attribute__((ext_vector_type(4))) short bf16x4;   // 4 bf16 (2 VGPRs)
typedef __attribute__((ext_vector_type(4))) float f32x4;    // MFMA acc

// f32 -> bf16 (round-to-nearest-even), bit-level
__device__ __forceinline__ short f2b(float f) {
    union { float f; uint32_t u; } v; v.f = f;
    uint32_t u = v.u;
    uint32_t r = (u + 0x7fffu + ((u >> 16) & 1u)) >> 16;
    return (short)r;
}

// ---------------------------------------------------------------------------
// Kernel 1: out[t, 0:288] = ent[trig_ent[t]];  out[t, 288:544] = 0.
__global__ void __launch_bounds__(256)
k_init(const float* __restrict__ ent, const int* __restrict__ trig_ent,
       float* __restrict__ out)
{
    const int t    = blockIdx.x * 4 + (threadIdx.x >> 6);
    const int lane = threadIdx.x & 63;
    const int e    = trig_ent[t];
    const float4* src = (const float4*)(ent + (size_t)e * ENT_DIM);  // 72 f4
    float4*       dst = (float4*)(out + (size_t)t * OUT_DIM);        // 136 f4
    const float4 z = {0.f, 0.f, 0.f, 0.f};
    dst[lane] = src[lane];                         // floats 0..255
    if (lane < 8) dst[64 + lane] = src[64 + lane]; // floats 256..287
    dst[72 + lane] = z;                            // floats 288..543
}

// ---------------------------------------------------------------------------
// Kernel 2: convert+transpose W_in/W_out f32[576][256] -> Wb bf16[2][256][576]
__global__ void __launch_bounds__(256)
k_prep(const float* __restrict__ W_in, const float* __restrict__ W_out,
       short* __restrict__ Wb)
{
    const int idx = blockIdx.x * 256 + threadIdx.x;     // 0 .. 2*576*256-1
    const int w   = idx / (ARG_DIM * ROLE_DIM);
    const int rem = idx % (ARG_DIM * ROLE_DIM);
    const int k   = rem / ROLE_DIM;
    const int col = rem % ROLE_DIM;
    const float* src = (w == 0) ? W_in : W_out;
    Wb[((size_t)w * ROLE_DIM + col) * ARG_DIM + k] = f2b(src[k * ROLE_DIM + col]);
}

// ---------------------------------------------------------------------------
// Counting sort of args by trigger: hist -> 2-level exclusive scan -> scatter.
__global__ void __launch_bounds__(256)
k_hist(const int* __restrict__ arg_trig, int* __restrict__ cnt)
{
    const int a = blockIdx.x * 256 + threadIdx.x;
    if (a < N_ARGS) atomicAdd(&cnt[arg_trig[a]], 1);
}

#define SCAN_T 1024
#define SCAN_B ((N_TRIG + SCAN_T - 1) / SCAN_T)   // 49

__global__ void __launch_bounds__(SCAN_T)
k_scan1(const int* __restrict__ cnt, int* __restrict__ off,
        int* __restrict__ bsum)
{
    __shared__ int buf[SCAN_T];
    const int tid = threadIdx.x;
    const int i   = blockIdx.x * SCAN_T + tid;
    int v = (i < N_TRIG) ? cnt[i] : 0;
    buf[tid] = v;
    __syncthreads();
#pragma unroll
    for (int o = 1; o < SCAN_T; o <<= 1) {
        int x = (tid >= o) ? buf[tid - o] : 0;
        __syncthreads();
        buf[tid] += x;
        __syncthreads();
    }
    if (i < N_TRIG) off[i] = buf[tid] - v;          // block-local exclusive
    if (tid == SCAN_T - 1) bsum[blockIdx.x] = buf[tid];
}

__global__ void __launch_bounds__(64)
k_scan2(int* __restrict__ bsum)
{
    if (threadIdx.x == 0) {
        int s = 0;
        for (int i = 0; i < SCAN_B; ++i) { int t = bsum[i]; bsum[i] = s; s += t; }
    }
}

__global__ void __launch_bounds__(SCAN_T)
k_scan3(int* __restrict__ off, const int* __restrict__ bsum)
{
    const int i = blockIdx.x * SCAN_T + threadIdx.x;
    if (i < N_TRIG) off[i] += bsum[blockIdx.x];
}

__global__ void __launch_bounds__(256)
k_scatter(const int* __restrict__ arg_trig, const int* __restrict__ off,
          int* __restrict__ cur, int* __restrict__ idx)
{
    const int a = blockIdx.x * 256 + threadIdx.x;
    if (a < N_ARGS) {
        const int t = arg_trig[a];
        const int p = atomicAdd(&cur[t], 1);
        idx[off[t] + p] = a;
    }
}

// ---------------------------------------------------------------------------
// Kernel 3: fused gather + bf16 MFMA GEMM + segmented (sorted) reduction.
//
// Rows are args in trigger-sorted order (idx[]). Main loop identical to R1
// (3-deep gather prefetch, double-buffered A LDS, B direct from L2-resident
// Wb, one raw barrier per K-step, lgkmcnt-only drain).
//
// Epilogue: stage 64x256 f32 tile to LDS, segmented run-reduction per column.
// Runs interior to a 32-row half-tile are COMPLETE sums (sorted) -> plain
// store. Runs touching half-tile boundaries -> atomicAdd partial. Atomic
// count drops 64M -> ~4M.
__global__ void __launch_bounds__(512, 4)
k_gemm(const float* __restrict__ ent,  const float* __restrict__ rel,
       const float* __restrict__ rtab, const short* __restrict__ Wb,
       const int* __restrict__ rtype_ids, const int* __restrict__ arg_trig,
       const int* __restrict__ arg_rel,   const int* __restrict__ arg_ent,
       const int* __restrict__ arg_is_in, const int* __restrict__ idx,
       float* __restrict__ out)
{
    __shared__ short As[2][BM][LDP];     // double-buffered A chunk (10 KB)
    __shared__ float Cs[BM][CSP];        // epilogue staging (64.5 KB)
    __shared__ int s_rel[BM], s_ent[BM], s_rt[BM], s_trig[BM], s_mask[BM];

    const int tid = threadIdx.x;
    const int a0  = blockIdx.x * BM;

    // Per-arg metadata via sorted index (mask: 1 = W_in, 0 = W_out, -1 = pad)
    if (tid < BM) {
        int i     = a0 + tid;
        int valid = (i < N_ARGS);
        int a     = idx[valid ? i : (N_ARGS - 1)];
        int r     = arg_rel[a];
        s_rel[tid]  = r;
        s_ent[tid]  = arg_ent[a];
        s_rt[tid]   = rtype_ids[r];
        s_trig[tid] = valid ? arg_trig[a] : -1;
        s_mask[tid] = valid ? arg_is_in[a] : -1;
    }
    __syncthreads();

    const int lane  = tid & 63;
    const int wave  = tid >> 6;          // 0..7
    const int quad  = lane >> 4;
    const int l15   = lane & 15;
    const int nbase = wave * 32;

    // A-staging coords: thread handles row = tid>>3, 4 floats at (tid&7)*4
    const int srow = tid >> 3;           // 0..63
    const int skq  = (tid & 7) * 4;      // 0..28

    // Per-row gather base pointers (srow fixed per thread)
    const float* p_rel = rel  + (size_t)s_rel[srow] * REL_R    + skq;
    const float* p_rt  = rtab + s_rt[srow] * RTYPE_DIM         + skq;
    const float* p_ent = ent  + (size_t)s_ent[srow] * ENT_DIM  + skq;

    // B fragment base: col = nbase + l15 (+n*16), k = s*32 + quad*8
    const short* wbl = Wb + (size_t)(nbase + l15) * ARG_DIM + quad * 8;

    // A-fragment row for m-tile m is m*16 + l15 -> per-lane scalar mask
    int rowmask[4];
#pragma unroll
    for (int m = 0; m < 4; ++m) rowmask[m] = s_mask[m * 16 + l15];

    f32x4 acc[4][2];
#pragma unroll
    for (int m = 0; m < 4; ++m)
#pragma unroll
        for (int n = 0; n < 2; ++n) acc[m][n] = (f32x4){0.f, 0.f, 0.f, 0.f};

    const bf16x8 zf = {0, 0, 0, 0, 0, 0, 0, 0};

    // 3-deep gather prefetch (steps 0..2 are all in the rel region)
    float4 vA = *(const float4*)(p_rel);
    float4 vB = *(const float4*)(p_rel + BK);
    float4 vC = *(const float4*)(p_rel + 2 * BK);

    auto STEP = [&](int s, float4& w) {
        // ---- convert + store the A slice prefetched 3 steps ago ----
        bf16x4 h;
        h[0] = f2b(w.x); h[1] = f2b(w.y); h[2] = f2b(w.z); h[3] = f2b(w.w);
        *(bf16x4*)&As[s & 1][srow][skq] = h;

        // ---- make LDS writes visible; do NOT drain vmcnt ----
        asm volatile("s_waitcnt lgkmcnt(0)" ::: "memory");
        __builtin_amdgcn_s_barrier();
        asm volatile("" ::: "memory");   // block load hoist above the barrier

        // ---- A fragments from LDS ----
        bf16x8 a[4];
#pragma unroll
        for (int m = 0; m < 4; ++m)
            a[m] = *(const bf16x8*)&As[s & 1][m * 16 + l15][quad * 8];

        // ---- B fragments direct from L2-resident Wb ----
        const short* bp = wbl + s * BK;
        const bf16x8 bi0 = *(const bf16x8*)(bp);
        const bf16x8 bi1 = *(const bf16x8*)(bp + 16 * ARG_DIM);
        const bf16x8 bo0 = *(const bf16x8*)(bp + (size_t)ROLE_DIM * ARG_DIM);
        const bf16x8 bo1 = *(const bf16x8*)(bp + (size_t)(ROLE_DIM + 16) * ARG_DIM);

        // ---- masked double-MFMA ----
#pragma unroll
        for (int m = 0; m < 4; ++m) {
            const bf16x8 ain = (rowmask[m] == 1) ? a[m] : zf;
            const bf16x8 aot = (rowmask[m] == 0) ? a[m] : zf;
            acc[m][0] = __builtin_amdgcn_mfma_f32_16x16x32_bf16(ain, bi0, acc[m][0], 0, 0, 0);
            acc[m][0] = __builtin_amdgcn_mfma_f32_16x16x32_bf16(aot, bo0, acc[m][0], 0, 0, 0);
            acc[m][1] = __builtin_amdgcn_mfma_f32_16x16x32_bf16(ain, bi1, acc[m][1], 0, 0, 0);
            acc[m][1] = __builtin_amdgcn_mfma_f32_16x16x32_bf16(aot, bo1, acc[m][1], 0, 0, 0);
        }

        // ---- issue gather for step s+3 (kept after B loads) ----
        __builtin_amdgcn_sched_barrier(0);
        if (s + 3 < NSTEP) {
            const int sn = s + 3;
            const float* src = (sn < 8)  ? (p_rel + sn * BK)
                             : (sn == 8) ? p_rt
                                         : (p_ent + (sn - 9) * BK);
            w = *(const float4*)src;
        }
    };

#pragma unroll
    for (int ss = 0; ss < NSTEP; ss += 3) {
        STEP(ss,     vA);
        STEP(ss + 1, vB);
        STEP(ss + 2, vC);
    }

    // ---- epilogue phase 1: stage accumulator tile to LDS ----
    // C/D layout: col = lane&15, row = quad*4 + reg  [m89-verified]
#pragma unroll
    for (int m = 0; m < 4; ++m)
#pragma unroll
        for (int n = 0; n < 2; ++n)
#pragma unroll
            for (int r4 = 0; r4 < 4; ++r4)
                Cs[m * 16 + quad * 4 + r4][nbase + n * 16 + l15] = acc[m][n][r4];
    __syncthreads();

    // ---- epilogue phase 2: segmented run-reduction (rows sorted by trig) ----
    // thread owns column c, scans rows [r0, r0+32). Branches are uniform
    // across each 256-thread half (all share the same run structure).
    {
        const int c    = tid & 255;
        const int half = tid >> 8;               // 0 or 1
        const int r0   = half * 32;
        const int rend = r0 + 32;

        int   runTrig  = s_trig[r0];
        int   runStart = r0;
        float sum      = 0.f;
        for (int r = r0; r < rend; ++r) {
            const int t = s_trig[r];
            if (t != runTrig) {
                if (runTrig >= 0) {
                    float* p = out + (size_t)runTrig * OUT_DIM + ENT_DIM + c;
                    if (runStart == r0) atomicAdd(p, sum);   // may extend left
                    else                *p = sum;            // complete sum
                }
                runTrig = t; runStart = r; sum = 0.f;
            }
            sum += Cs[r][c];
        }
        if (runTrig >= 0) {                                  // touches rend-1
            float* p = out + (size_t)runTrig * OUT_DIM + ENT_DIM + c;
            atomicAdd(p, sum);                               // may extend right
        }
    }
}

// ---------------------------------------------------------------------------
extern "C" void kernel_launch(void* const* d_in, const int* in_sizes, int n_in,
                              void* d_out, int out_size, void* d_ws, size_t ws_size,
                              hipStream_t stream)
{
    const float* ent      = (const float*)d_in[0];   // [N_ENT, 288]
    const float* rel      = (const float*)d_in[1];   // [N_REL, 256]
    const float* rtab     = (const float*)d_in[2];   // [201, 32]
    const float* W_in     = (const float*)d_in[3];   // [576, 256]
    const float* W_out    = (const float*)d_in[4];   // [576, 256]
    const int*  rtype_ids = (const int*)d_in[5];
    const int*  trig_ent  = (const int*)d_in[6];
    const int*  arg_trig  = (const int*)d_in[7];
    const int*  arg_rel   = (const int*)d_in[8];
    const int*  arg_ent   = (const int*)d_in[9];
    const int*  arg_is_in = (const int*)d_in[10];

    float* out = (float*)d_out;                      // [N_TRIG, 544] f32

    // Workspace layout (bytes):
    //   Wb   : [0, 589824)                bf16 [2][256][576]
    //   cnt  : [589824, 789824)           int  [50000]
    //   cur  : [789824, 989824)           int  [50000]
    //   off  : [989824, 1189824)          int  [50000]
    //   bsum : [1190080, 1190400)         int  [49] (padded)
    //   idx  : [1190400, 2190400)         int  [250000]
    char* ws   = (char*)d_ws;
    short* Wb  = (short*)(ws);
    int*   cnt = (int*)(ws + 589824);
    int*   cur = (int*)(ws + 789824);
    int*   off = (int*)(ws + 989824);
    int*   bsum= (int*)(ws + 1190080);
    int*   idx = (int*)(ws + 1190400);

    hipMemsetAsync(cnt, 0, 400000, stream);          // cnt + cur

    hipLaunchKernelGGL(k_init, dim3(N_TRIG / 4), dim3(256), 0, stream,
                       ent, trig_ent, out);
    hipLaunchKernelGGL(k_prep, dim3(2 * ARG_DIM * ROLE_DIM / 256), dim3(256), 0,
                       stream, W_in, W_out, Wb);
    hipLaunchKernelGGL(k_hist, dim3((N_ARGS + 255) / 256), dim3(256), 0, stream,
                       arg_trig, cnt);
    hipLaunchKernelGGL(k_scan1, dim3(SCAN_B), dim3(SCAN_T), 0, stream,
                       cnt, off, bsum);
    hipLaunchKernelGGL(k_scan2, dim3(1), dim3(64), 0, stream, bsum);
    hipLaunchKernelGGL(k_scan3, dim3(SCAN_B), dim3(SCAN_T), 0, stream,
                       off, bsum);
    hipLaunchKernelGGL(k_scatter, dim3((N_ARGS + 255) / 256), dim3(256), 0,
                       stream, arg_trig, off, cur, idx);
    hipLaunchKernelGGL(k_gemm, dim3((N_ARGS + BM - 1) / BM), dim3(512), 0, stream,
                       ent, rel, rtab, Wb,
                       rtype_ids, arg_trig, arg_rel, arg_ent, arg_is_in, idx, out);
}

// Round 3
// 755.355 us; speedup vs baseline: 1.1492x; 1.0611x over previous
//
#include <hip/hip_runtime.h>
#include <hip/hip_bf16.h>
#include <stdint.h>

// Problem constants (from reference)
#define N_ENT    100000
#define N_REL    250000
#define N_TRIG   50000
#define N_ARGS   250000
#define ENT_DIM  288
#define REL_R    256
#define RTYPE_DIM 32
#define ROLE_DIM 256
#define ARG_DIM  576           // REL_R + RTYPE_DIM + ENT_DIM
#define OUT_DIM  544           // ENT_DIM + ROLE_DIM

// GEMM tiling
#define BM 64                  // args per block
#define BK 32                  // K chunk (one MFMA K-step)
#define NSTEP (ARG_DIM / BK)   // 18
#define LDPK 584               // full-K LDS row stride in shorts (576+8):
                               // 1168 B rows, 16B-aligned b128 frags
#define CSP 258                // Cs padded row stride (floats)

typedef __attribute__((ext_vector_type(8))) short bf16x8;   // 8 bf16 (4 VGPRs)
typedef __attribute__((ext_vector_type(4))) short bf16x4;   // 4 bf16 (2 VGPRs)
typedef __attribute__((ext_vector_type(4))) float f32x4;    // MFMA acc

// f32 -> bf16 (round-to-nearest-even), bit-level
__device__ __forceinline__ short f2b(float f) {
    union { float f; uint32_t u; } v; v.f = f;
    uint32_t u = v.u;
    uint32_t r = (u + 0x7fffu + ((u >> 16) & 1u)) >> 16;
    return (short)r;
}

// ---------------------------------------------------------------------------
// Kernel 1: out[t, 0:288] = ent[trig_ent[t]];  out[t, 288:544] = 0.
__global__ void __launch_bounds__(256)
k_init(const float* __restrict__ ent, const int* __restrict__ trig_ent,
       float* __restrict__ out)
{
    const int t    = blockIdx.x * 4 + (threadIdx.x >> 6);
    const int lane = threadIdx.x & 63;
    const int e    = trig_ent[t];
    const float4* src = (const float4*)(ent + (size_t)e * ENT_DIM);  // 72 f4
    float4*       dst = (float4*)(out + (size_t)t * OUT_DIM);        // 136 f4
    const float4 z = {0.f, 0.f, 0.f, 0.f};
    dst[lane] = src[lane];                         // floats 0..255
    if (lane < 8) dst[64 + lane] = src[64 + lane]; // floats 256..287
    dst[72 + lane] = z;                            // floats 288..543
}

// ---------------------------------------------------------------------------
// Kernel 2 (fused): W convert+transpose  AND  trigger histogram.
// prep: Wb bf16[2][256][576], per-column contiguous k. hist: cnt[trig]++.
__global__ void __launch_bounds__(256)
k_prep_hist(const float* __restrict__ W_in, const float* __restrict__ W_out,
            short* __restrict__ Wb,
            const int* __restrict__ arg_trig, int* __restrict__ cnt)
{
    const int idx = blockIdx.x * 256 + threadIdx.x;     // 0 .. 294911
    {
        const int w   = idx / (ARG_DIM * ROLE_DIM);
        const int rem = idx % (ARG_DIM * ROLE_DIM);
        const int k   = rem / ROLE_DIM;
        const int col = rem % ROLE_DIM;
        const float* src = (w == 0) ? W_in : W_out;
        Wb[((size_t)w * ROLE_DIM + col) * ARG_DIM + k] = f2b(src[k * ROLE_DIM + col]);
    }
    if (idx < N_ARGS) atomicAdd(&cnt[arg_trig[idx]], 1);
}

// ---------------------------------------------------------------------------
// Counting sort (by trigger): scan1 -> scan3 (internal block prefix) -> scatter
#define SCAN_T 1024
#define SCAN_B ((N_TRIG + SCAN_T - 1) / SCAN_T)   // 49

__global__ void __launch_bounds__(SCAN_T)
k_scan1(const int* __restrict__ cnt, int* __restrict__ off,
        int* __restrict__ bsum)
{
    __shared__ int buf[SCAN_T];
    const int tid = threadIdx.x;
    const int i   = blockIdx.x * SCAN_T + tid;
    int v = (i < N_TRIG) ? cnt[i] : 0;
    buf[tid] = v;
    __syncthreads();
#pragma unroll
    for (int o = 1; o < SCAN_T; o <<= 1) {
        int x = (tid >= o) ? buf[tid - o] : 0;
        __syncthreads();
        buf[tid] += x;
        __syncthreads();
    }
    if (i < N_TRIG) off[i] = buf[tid] - v;          // block-local exclusive
    if (tid == SCAN_T - 1) bsum[blockIdx.x] = buf[tid];
}

__global__ void __launch_bounds__(SCAN_T)
k_scan3(int* __restrict__ off, const int* __restrict__ bsum)
{
    __shared__ int sh;
    if (threadIdx.x == 0) {                          // serial prefix, <=48 adds
        int s = 0;
        for (int j = 0; j < (int)blockIdx.x; ++j) s += bsum[j];
        sh = s;
    }
    __syncthreads();
    const int i = blockIdx.x * SCAN_T + threadIdx.x;
    if (i < N_TRIG) off[i] += sh;
}

// scatter allocates slots by bumping off[t] (off is dead afterwards)
__global__ void __launch_bounds__(256)
k_scatter(const int* __restrict__ arg_trig, int* __restrict__ off,
          int* __restrict__ idx)
{
    const int a = blockIdx.x * 256 + threadIdx.x;
    if (a < N_ARGS) {
        const int p = atomicAdd(&off[arg_trig[a]], 1);
        idx[p] = a;
    }
}

// ---------------------------------------------------------------------------
// Kernel 3: fused gather + bf16 MFMA GEMM + segmented (sorted) reduction.
//
// v3: WHOLE-ROW burst staging. Each thread owns row tid>>3, float-offset
// (tid&7)*4; it burst-issues 9 float4 loads covering [rel row | rtype]
// (contiguous 1KB+128B), converts to bf16 into LDS, then 9 more covering the
// ent row (contiguous 1152B). DRAM sees each gathered row as one contiguous
// burst instead of 18 temporally-scattered 128B slices (R2's ~1 TB/s cap).
//
// Compute phase is barrier-free: A from LDS (full K resident), B direct from
// L2-resident Wb, 16 masked double-MFMAs per step. Epilogue reuses the As
// footprint for the Cs staging tile (segmented run-reduction, sorted rows).
__global__ void __launch_bounds__(512, 4)
k_gemm(const float* __restrict__ ent,  const float* __restrict__ rel,
       const float* __restrict__ rtab, const short* __restrict__ Wb,
       const int* __restrict__ rtype_ids, const int* __restrict__ arg_trig,
       const int* __restrict__ arg_rel,   const int* __restrict__ arg_ent,
       const int* __restrict__ arg_is_in, const int* __restrict__ idx,
       float* __restrict__ out)
{
    __shared__ alignas(16) short As[BM][LDPK];   // 74,752 B; aliased by Cs
    __shared__ int s_rel[BM], s_ent[BM], s_rt[BM], s_trig[BM], s_mask[BM];

    const int tid = threadIdx.x;
    const int a0  = blockIdx.x * BM;

    // Per-arg metadata via sorted index (mask: 1 = W_in, 0 = W_out, -1 = pad)
    if (tid < BM) {
        int i     = a0 + tid;
        int valid = (i < N_ARGS);
        int a     = idx[valid ? i : (N_ARGS - 1)];
        int r     = arg_rel[a];
        s_rel[tid]  = r;
        s_ent[tid]  = arg_ent[a];
        s_rt[tid]   = rtype_ids[r];
        s_trig[tid] = valid ? arg_trig[a] : -1;
        s_mask[tid] = valid ? arg_is_in[a] : -1;
    }
    __syncthreads();

    const int lane  = tid & 63;
    const int wave  = tid >> 6;          // 0..7
    const int quad  = lane >> 4;
    const int l15   = lane & 15;
    const int nbase = wave * 32;

    const int srow = tid >> 3;           // 0..63  (8 threads per row)
    const int skq  = (tid & 7) * 4;      // float offset within 32-chunk

    const float* p_rel = rel  + (size_t)s_rel[srow] * REL_R    + skq;
    const float* p_rt  = rtab + s_rt[srow] * RTYPE_DIM         + skq;
    const float* p_ent = ent  + (size_t)s_ent[srow] * ENT_DIM  + skq;

    // ---- burst-stage group A: rel row (chunks 0..7) + rtype (chunk 8) ----
    {
        float4 t[9];
#pragma unroll
        for (int s = 0; s < 8; ++s) t[s] = *(const float4*)(p_rel + s * BK);
        t[8] = *(const float4*)p_rt;
#pragma unroll
        for (int s = 0; s < 9; ++s) {
            bf16x4 h;
            h[0] = f2b(t[s].x); h[1] = f2b(t[s].y);
            h[2] = f2b(t[s].z); h[3] = f2b(t[s].w);
            *(bf16x4*)&As[srow][s * BK + skq] = h;
        }
    }
    // ---- burst-stage group B: ent row (chunks 9..17) ----
    {
        float4 t[9];
#pragma unroll
        for (int s = 0; s < 9; ++s) t[s] = *(const float4*)(p_ent + s * BK);
#pragma unroll
        for (int s = 0; s < 9; ++s) {
            bf16x4 h;
            h[0] = f2b(t[s].x); h[1] = f2b(t[s].y);
            h[2] = f2b(t[s].z); h[3] = f2b(t[s].w);
            *(bf16x4*)&As[srow][(s + 9) * BK + skq] = h;
        }
    }

    // A-fragment row for m-tile m is m*16 + l15 -> per-lane scalar mask
    int rowmask[4];
#pragma unroll
    for (int m = 0; m < 4; ++m) rowmask[m] = s_mask[m * 16 + l15];

    f32x4 acc[4][2];
#pragma unroll
    for (int m = 0; m < 4; ++m)
#pragma unroll
        for (int n = 0; n < 2; ++n) acc[m][n] = (f32x4){0.f, 0.f, 0.f, 0.f};

    // B fragment base: col = nbase + l15 (+n*16), k = s*32 + quad*8
    const short* wbl = Wb + (size_t)(nbase + l15) * ARG_DIM + quad * 8;
    const bf16x8 zf = {0, 0, 0, 0, 0, 0, 0, 0};

    __syncthreads();   // A panel fully staged

    // ---- barrier-free compute: 18 steps, compiler pipelines B loads ----
#pragma unroll
    for (int s = 0; s < NSTEP; ++s) {
        const short* bp = wbl + s * BK;
        const bf16x8 bi0 = *(const bf16x8*)(bp);
        const bf16x8 bi1 = *(const bf16x8*)(bp + 16 * ARG_DIM);
        const bf16x8 bo0 = *(const bf16x8*)(bp + (size_t)ROLE_DIM * ARG_DIM);
        const bf16x8 bo1 = *(const bf16x8*)(bp + (size_t)(ROLE_DIM + 16) * ARG_DIM);

        bf16x8 a[4];
#pragma unroll
        for (int m = 0; m < 4; ++m)
            a[m] = *(const bf16x8*)&As[m * 16 + l15][s * BK + quad * 8];

#pragma unroll
        for (int m = 0; m < 4; ++m) {
            const bf16x8 ain = (rowmask[m] == 1) ? a[m] : zf;
            const bf16x8 aot = (rowmask[m] == 0) ? a[m] : zf;
            acc[m][0] = __builtin_amdgcn_mfma_f32_16x16x32_bf16(ain, bi0, acc[m][0], 0, 0, 0);
            acc[m][0] = __builtin_amdgcn_mfma_f32_16x16x32_bf16(aot, bo0, acc[m][0], 0, 0, 0);
            acc[m][1] = __builtin_amdgcn_mfma_f32_16x16x32_bf16(ain, bi1, acc[m][1], 0, 0, 0);
            acc[m][1] = __builtin_amdgcn_mfma_f32_16x16x32_bf16(aot, bo1, acc[m][1], 0, 0, 0);
        }
    }

    // ---- epilogue phase 1: stage accumulator tile into Cs (aliases As) ----
    __syncthreads();   // all A reads done before overwrite
    float (*Cs)[CSP] = (float(*)[CSP])&As[0][0];   // 66,048 B <= 74,752 B
#pragma unroll
    for (int m = 0; m < 4; ++m)
#pragma unroll
        for (int n = 0; n < 2; ++n)
#pragma unroll
            for (int r4 = 0; r4 < 4; ++r4)
                Cs[m * 16 + quad * 4 + r4][nbase + n * 16 + l15] = acc[m][n][r4];
    __syncthreads();

    // ---- epilogue phase 2: segmented run-reduction (rows sorted by trig) ----
    {
        const int c    = tid & 255;
        const int half = tid >> 8;               // 0 or 1
        const int r0   = half * 32;
        const int rend = r0 + 32;

        int   runTrig  = s_trig[r0];
        int   runStart = r0;
        float sum      = 0.f;
        for (int r = r0; r < rend; ++r) {
            const int t = s_trig[r];
            if (t != runTrig) {
                if (runTrig >= 0) {
                    float* p = out + (size_t)runTrig * OUT_DIM + ENT_DIM + c;
                    if (runStart == r0) atomicAdd(p, sum);   // may extend left
                    else                *p = sum;            // complete sum
                }
                runTrig = t; runStart = r; sum = 0.f;
            }
            sum += Cs[r][c];
        }
        if (runTrig >= 0) {                                  // touches rend-1
            float* p = out + (size_t)runTrig * OUT_DIM + ENT_DIM + c;
            atomicAdd(p, sum);                               // may extend right
        }
    }
}

// ---------------------------------------------------------------------------
extern "C" void kernel_launch(void* const* d_in, const int* in_sizes, int n_in,
                              void* d_out, int out_size, void* d_ws, size_t ws_size,
                              hipStream_t stream)
{
    const float* ent      = (const float*)d_in[0];   // [N_ENT, 288]
    const float* rel      = (const float*)d_in[1];   // [N_REL, 256]
    const float* rtab     = (const float*)d_in[2];   // [201, 32]
    const float* W_in     = (const float*)d_in[3];   // [576, 256]
    const float* W_out    = (const float*)d_in[4];   // [576, 256]
    const int*  rtype_ids = (const int*)d_in[5];
    const int*  trig_ent  = (const int*)d_in[6];
    const int*  arg_trig  = (const int*)d_in[7];
    const int*  arg_rel   = (const int*)d_in[8];
    const int*  arg_ent   = (const int*)d_in[9];
    const int*  arg_is_in = (const int*)d_in[10];

    float* out = (float*)d_out;                      // [N_TRIG, 544] f32

    // Workspace layout (bytes):
    //   Wb   : [0, 589824)          bf16 [2][256][576]
    //   cnt  : [589824, 789824)     int [50000]
    //   off  : [789824, 989824)     int [50000]
    //   bsum : [989824, 990080)     int [49] (padded)
    //   idx  : [990080, 1990080)    int [250000]
    char* ws   = (char*)d_ws;
    short* Wb  = (short*)(ws);
    int*   cnt = (int*)(ws + 589824);
    int*   off = (int*)(ws + 789824);
    int*   bsum= (int*)(ws + 989824);
    int*   idx = (int*)(ws + 990080);

    hipMemsetAsync(cnt, 0, 200000, stream);

    hipLaunchKernelGGL(k_init, dim3(N_TRIG / 4), dim3(256), 0, stream,
                       ent, trig_ent, out);
    hipLaunchKernelGGL(k_prep_hist, dim3(2 * ARG_DIM * ROLE_DIM / 256), dim3(256),
                       0, stream, W_in, W_out, Wb, arg_trig, cnt);
    hipLaunchKernelGGL(k_scan1, dim3(SCAN_B), dim3(SCAN_T), 0, stream,
                       cnt, off, bsum);
    hipLaunchKernelGGL(k_scan3, dim3(SCAN_B), dim3(SCAN_T), 0, stream,
                       off, bsum);
    hipLaunchKernelGGL(k_scatter, dim3((N_ARGS + 255) / 256), dim3(256), 0,
                       stream, arg_trig, off, idx);
    hipLaunchKernelGGL(k_gemm, dim3((N_ARGS + BM - 1) / BM), dim3(512), 0, stream,
                       ent, rel, rtab, Wb,
                       rtype_ids, arg_trig, arg_rel, arg_ent, arg_is_in, idx, out);
}